// Round 1
// baseline (767.971 us; speedup 1.0000x reference)
//
#include <hip/hip_runtime.h>

// GraphSAGE-style net: 2x SAGE(mean) + skip + MLP head, fp32.
// N=50000 nodes, E=800000 edges/layer, D=128, H=256, O=3.
//
// Structure:
//   CSR build per edge list (histogram -> single-block scan -> fill)
//   agg = mean of neighbor rows (gather over CSR, 32 threads/node, float4)
//   h1 = agg@Wl1.T + x@Wr1.T + bl1              (fused multi-A GEMM)
//   agg2 = mean over edge list 2 of h1
//   h3 = agg2@Wl2.T + h1@Wr2.T + x@Ws.T + bl2+bs
//   h4 = relu(h3@W1.T + b1)
//   out = h4@W2.T + b2                          (wave-per-row reduce)

#define DD  128   // feature dim
#define LDT 132   // padded LDS stride in floats (pad 4 keeps float4 align, breaks bank stride)

__device__ inline float dot4(float4 a, float4 b) {
    return a.x * b.x + a.y * b.y + a.z * b.z + a.w * b.w;
}

// ---------------- CSR build ----------------
__global__ __launch_bounds__(256) void init_kernel(int* __restrict__ d0, int* __restrict__ f0,
                                                   int* __restrict__ d1, int* __restrict__ f1, int n) {
    int i = blockIdx.x * 256 + threadIdx.x;
    if (i < n) { d0[i] = 0; f0[i] = 0; d1[i] = 0; f1[i] = 0; }
}

__global__ __launch_bounds__(256) void hist_kernel(const int* __restrict__ dst0, int* __restrict__ deg0,
                                                   const int* __restrict__ dst1, int* __restrict__ deg1,
                                                   int e0, int e1) {
    int e = blockIdx.x * 256 + threadIdx.x;
    if (e < e0) atomicAdd(&deg0[dst0[e]], 1);
    if (e < e1) atomicAdd(&deg1[dst1[e]], 1);
}

// exclusive prefix sum of deg -> rp. One block per array (grid=2), 1024 threads.
__global__ __launch_bounds__(1024) void scan_kernel(const int* __restrict__ deg0, int* __restrict__ rp0,
                                                    const int* __restrict__ deg1, int* __restrict__ rp1,
                                                    int n) {
    const int* deg = blockIdx.x ? deg1 : deg0;
    int* rp = blockIdx.x ? rp1 : rp0;
    __shared__ int sums[1024];
    int t = threadIdx.x;
    int chunk = (n + 1023) >> 10;
    int lo = t * chunk;
    int hi = min(n, lo + chunk);
    int s = 0;
    for (int i = lo; i < hi; ++i) s += deg[i];
    sums[t] = s;
    __syncthreads();
    // Hillis-Steele inclusive scan over 1024 partials
    for (int off = 1; off < 1024; off <<= 1) {
        int v = (t >= off) ? sums[t - off] : 0;
        __syncthreads();
        sums[t] += v;
        __syncthreads();
    }
    int run = (t == 0) ? 0 : sums[t - 1];
    for (int i = lo; i < hi; ++i) { rp[i] = run; run += deg[i]; }
}

__global__ __launch_bounds__(256) void fill_kernel(
    const int* __restrict__ src0, const int* __restrict__ dst0, const int* __restrict__ rp0,
    int* __restrict__ f0, int* __restrict__ csr0,
    const int* __restrict__ src1, const int* __restrict__ dst1, const int* __restrict__ rp1,
    int* __restrict__ f1, int* __restrict__ csr1, int e0, int e1) {
    int e = blockIdx.x * 256 + threadIdx.x;
    if (e < e0) { int d = dst0[e]; int p = atomicAdd(&f0[d], 1); csr0[rp0[d] + p] = src0[e]; }
    if (e < e1) { int d = dst1[e]; int p = atomicAdd(&f1[d], 1); csr1[rp1[d] + p] = src1[e]; }
}

// ---------------- mean aggregation: gather over CSR ----------------
// 32 threads per node (float4 per lane covers 128 floats), no atomics.
__global__ __launch_bounds__(256) void agg_mean_kernel(const float* __restrict__ X,
                                                       const int* __restrict__ csr,
                                                       const int* __restrict__ rp,
                                                       const int* __restrict__ deg,
                                                       float* __restrict__ out, int n) {
    int g = (blockIdx.x * 256 + threadIdx.x) >> 5;
    int lane = threadIdx.x & 31;
    if (g >= n) return;
    int start = rp[g];
    int d = deg[g];
    int end = start + d;
    const float4* X4 = (const float4*)X;
    float4 acc = make_float4(0.f, 0.f, 0.f, 0.f);
    int e = start;
    for (; e + 1 < end; e += 2) {   // 2-way unroll: independent loads in flight
        int s0 = csr[e], s1 = csr[e + 1];
        float4 v0 = X4[(size_t)s0 * 32 + lane];
        float4 v1 = X4[(size_t)s1 * 32 + lane];
        acc.x += v0.x + v1.x; acc.y += v0.y + v1.y;
        acc.z += v0.z + v1.z; acc.w += v0.w + v1.w;
    }
    if (e < end) {
        int s0 = csr[e];
        float4 v0 = X4[(size_t)s0 * 32 + lane];
        acc.x += v0.x; acc.y += v0.y; acc.z += v0.z; acc.w += v0.w;
    }
    float scale = 1.0f / (float)max(d, 1);
    float4 r = make_float4(acc.x * scale, acc.y * scale, acc.z * scale, acc.w * scale);
    ((float4*)out)[(size_t)g * 32 + lane] = r;
}

// ---------------- fused multi-input GEMM: C = sum_p A_p @ W_p.T (+b0 +b1) [relu] ----------------
// All A_p are [M x 128], W_p are [NC x 128] row-major. BM=64, BN=64, K=128, 256 thr, 4x4 microtile.
// LDS: A tile + W tile, padded stride 132 (2-way max bank aliasing on reads = free).
template <int NPAIR, bool RELU>
__global__ __launch_bounds__(256) void gemm_kernel(
    const float* __restrict__ A0, const float* __restrict__ W0,
    const float* __restrict__ A1, const float* __restrict__ W1,
    const float* __restrict__ A2, const float* __restrict__ W2,
    const float* __restrict__ bias0, const float* __restrict__ bias1,
    float* __restrict__ C, int M, int NC) {
    __shared__ float As[64 * LDT];
    __shared__ float Bs[64 * LDT];
    const int t = threadIdx.x;
    const int nCB = NC >> 6;
    const int rowBase = (blockIdx.x / nCB) * 64;
    const int colBase = (blockIdx.x % nCB) * 64;
    const int tx = t & 15;   // cols: tx + 16*c  (bank-friendly spread)
    const int ty = t >> 4;   // rows: 4*ty + r
    const float* Ap[3] = {A0, A1, A2};
    const float* Wp[3] = {W0, W1, W2};

    float acc[4][4];
#pragma unroll
    for (int r = 0; r < 4; ++r)
#pragma unroll
        for (int c = 0; c < 4; ++c) acc[r][c] = 0.f;

    for (int p = 0; p < NPAIR; ++p) {
        const float* A = Ap[p];
        const float* W = Wp[p];
        // stage 64x128 tiles of A and W (coalesced float4)
#pragma unroll
        for (int i = 0; i < 8; ++i) {
            int idx = t + 256 * i;           // 0..2047
            int row = idx >> 5;
            int c4 = (idx & 31) << 2;
            float4 v = make_float4(0.f, 0.f, 0.f, 0.f);
            int gr = rowBase + row;
            if (gr < M) v = *(const float4*)&A[(size_t)gr * DD + c4];
            *(float4*)&As[row * LDT + c4] = v;
            float4 wv = *(const float4*)&W[(size_t)(colBase + row) * DD + c4];
            *(float4*)&Bs[row * LDT + c4] = wv;
        }
        __syncthreads();
#pragma unroll 4
        for (int k = 0; k < DD; k += 4) {
            float4 a[4], b[4];
#pragma unroll
            for (int r = 0; r < 4; ++r) a[r] = *(const float4*)&As[(4 * ty + r) * LDT + k];
#pragma unroll
            for (int c = 0; c < 4; ++c) b[c] = *(const float4*)&Bs[(tx + 16 * c) * LDT + k];
#pragma unroll
            for (int r = 0; r < 4; ++r)
#pragma unroll
                for (int c = 0; c < 4; ++c) acc[r][c] += dot4(a[r], b[c]);
        }
        __syncthreads();
    }

    float bv[4];
#pragma unroll
    for (int c = 0; c < 4; ++c) {
        int col = colBase + tx + 16 * c;
        float b = bias0 ? bias0[col] : 0.f;
        if (bias1) b += bias1[col];
        bv[c] = b;
    }
#pragma unroll
    for (int r = 0; r < 4; ++r) {
        int row = rowBase + 4 * ty + r;
        if (row < M) {
#pragma unroll
            for (int c = 0; c < 4; ++c) {
                float v = acc[r][c] + bv[c];
                if (RELU) v = fmaxf(v, 0.f);
                C[(size_t)row * NC + colBase + tx + 16 * c] = v;
            }
        }
    }
}

// ---------------- output layer: out[N,3] = h4 @ W2.T + b2, one wave per row ----------------
__global__ __launch_bounds__(256) void out_kernel(const float* __restrict__ h4,
                                                  const float* __restrict__ W2,
                                                  const float* __restrict__ b2,
                                                  float* __restrict__ out, int n) {
    int w = (blockIdx.x * 256 + threadIdx.x) >> 6;
    int lane = threadIdx.x & 63;
    if (w >= n) return;
    float4 h = *(const float4*)&h4[(size_t)w * 256 + lane * 4];
    float p0 = dot4(h, *(const float4*)&W2[0 * 256 + lane * 4]);
    float p1 = dot4(h, *(const float4*)&W2[1 * 256 + lane * 4]);
    float p2 = dot4(h, *(const float4*)&W2[2 * 256 + lane * 4]);
#pragma unroll
    for (int off = 32; off > 0; off >>= 1) {
        p0 += __shfl_xor(p0, off);
        p1 += __shfl_xor(p1, off);
        p2 += __shfl_xor(p2, off);
    }
    if (lane == 0) {
        out[(size_t)w * 3 + 0] = p0 + b2[0];
        out[(size_t)w * 3 + 1] = p1 + b2[1];
        out[(size_t)w * 3 + 2] = p2 + b2[2];
    }
}

extern "C" void kernel_launch(void* const* d_in, const int* in_sizes, int n_in,
                              void* d_out, int out_size, void* d_ws, size_t ws_size,
                              hipStream_t stream) {
    const float* x   = (const float*)d_in[0];
    const int*   ei0 = (const int*)d_in[1];
    const int*   ei1 = (const int*)d_in[2];
    const float* Wl1 = (const float*)d_in[3];
    const float* bl1 = (const float*)d_in[4];
    const float* Wr1 = (const float*)d_in[5];
    const float* Wl2 = (const float*)d_in[6];
    const float* bl2 = (const float*)d_in[7];
    const float* Wr2 = (const float*)d_in[8];
    const float* Wsk = (const float*)d_in[9];
    const float* bsk = (const float*)d_in[10];
    const float* W1  = (const float*)d_in[11];
    const float* b1  = (const float*)d_in[12];
    const float* W2  = (const float*)d_in[13];
    const float* b2  = (const float*)d_in[14];
    float* out = (float*)d_out;

    const int N  = in_sizes[0] / DD;   // 50000
    const int E0 = in_sizes[1] / 2;    // 800000
    const int E1 = in_sizes[2] / 2;
    const int H  = in_sizes[12];       // 256

    const int* src0 = ei0;      const int* dst0 = ei0 + E0;
    const int* src1 = ei1;      const int* dst1 = ei1 + E1;

    // workspace carve (~136 MB total)
    char* wp = (char*)d_ws;
    float* agg = (float*)wp; wp += (size_t)N * DD * sizeof(float);
    float* h1  = (float*)wp; wp += (size_t)N * DD * sizeof(float);
    float* h3  = (float*)wp; wp += (size_t)N * DD * sizeof(float);
    float* h4  = (float*)wp; wp += (size_t)N * H * sizeof(float);
    int* deg0 = (int*)wp; wp += (size_t)N * sizeof(int);
    int* rp0  = (int*)wp; wp += (size_t)N * sizeof(int);
    int* f0   = (int*)wp; wp += (size_t)N * sizeof(int);
    int* deg1 = (int*)wp; wp += (size_t)N * sizeof(int);
    int* rp1  = (int*)wp; wp += (size_t)N * sizeof(int);
    int* f1   = (int*)wp; wp += (size_t)N * sizeof(int);
    int* csr0 = (int*)wp; wp += (size_t)E0 * sizeof(int);
    int* csr1 = (int*)wp; wp += (size_t)E1 * sizeof(int);

    const int gN   = (N + 255) / 256;
    const int Emax = (E0 > E1) ? E0 : E1;
    const int gE   = (Emax + 255) / 256;
    const int gAgg = (N * 32 + 255) / 256;
    const int mB   = (N + 63) / 64;    // 782 row blocks

    init_kernel<<<gN, 256, 0, stream>>>(deg0, f0, deg1, f1, N);
    hist_kernel<<<gE, 256, 0, stream>>>(dst0, deg0, dst1, deg1, E0, E1);
    scan_kernel<<<2, 1024, 0, stream>>>(deg0, rp0, deg1, rp1, N);
    fill_kernel<<<gE, 256, 0, stream>>>(src0, dst0, rp0, f0, csr0,
                                        src1, dst1, rp1, f1, csr1, E0, E1);

    // layer 1: agg1 = mean_j x_j ; h1 = agg1@Wl1.T + x@Wr1.T + bl1
    agg_mean_kernel<<<gAgg, 256, 0, stream>>>(x, csr0, rp0, deg0, agg, N);
    gemm_kernel<2, false><<<mB * (DD / 64), 256, 0, stream>>>(
        agg, Wl1, x, Wr1, nullptr, nullptr, bl1, nullptr, h1, N, DD);

    // layer 2 + skip: agg2 = mean_j h1_j ; h3 = agg2@Wl2.T + h1@Wr2.T + x@Ws.T + bl2 + bs
    agg_mean_kernel<<<gAgg, 256, 0, stream>>>(h1, csr1, rp1, deg1, agg, N);
    gemm_kernel<3, false><<<mB * (DD / 64), 256, 0, stream>>>(
        agg, Wl2, h1, Wr2, x, Wsk, bl2, bsk, h3, N, DD);

    // MLP: h4 = relu(h3@W1.T + b1) ; out = h4@W2.T + b2
    gemm_kernel<1, true><<<mB * (H / 64), 256, 0, stream>>>(
        h3, W1, nullptr, nullptr, nullptr, nullptr, b1, nullptr, h4, N, H);

    const int gOut = (N * 64 + 255) / 256;
    out_kernel<<<gOut, 256, 0, stream>>>(h4, W2, b2, out, N);
}

// Round 2
// 497.980 us; speedup vs baseline: 1.5422x; 1.5422x over previous
//
#include <hip/hip_runtime.h>
#include <hip/hip_bf16.h>

// GraphSAGE net on MI355X: bf16 MFMA GEMMs + bf16 gather aggregation.
// N=50000, E=800000/layer, D=128, H=256, O=3.
//
// Pipeline:
//   cast x + 6 weight mats fp32->bf16 (one fused kernel)
//   CSR build per edge list (hist -> scan -> fill)
//   agg = mean neighbor rows (bf16 gather, fp32 accum)
//   h1 = agg@Wl1.T + x@Wr1.T + bl1                     (MFMA, bf16 out)
//   h3 = agg2@Wl2.T + h1@Wr2.T + x@Ws.T + bl2 + bs    (MFMA, bf16 out)
//   h4 = relu(h3@W1.T + b1)                            (MFMA, bf16 out)
//   out = h4@W2.T + b2                                 (fp32 wave-reduce)

#define DD 128
typedef unsigned short u16;
typedef __attribute__((ext_vector_type(8))) short short8;
typedef __attribute__((ext_vector_type(4))) float f32x4;

__device__ inline u16 f2bf(float f) {
    __hip_bfloat16 h = __float2bfloat16(f);
    u16 u;
    __builtin_memcpy(&u, &h, 2);
    return u;
}
__device__ inline float bf_lo(unsigned u) { union { unsigned x; float f; } c; c.x = u << 16; return c.f; }
__device__ inline float bf_hi(unsigned u) { union { unsigned x; float f; } c; c.x = u & 0xffff0000u; return c.f; }

// ---------------- fused fp32 -> bf16 cast ----------------
struct CastJobs {
    const float4* src[7];
    uint2* dst[7];
    int qstart[8];   // quad-index prefix; qstart[7] = total
};
__global__ __launch_bounds__(256) void cast_kernel(CastJobs jb) {
    int q = blockIdx.x * 256 + threadIdx.x;
    if (q >= jb.qstart[7]) return;
    int i = 0;
#pragma unroll
    for (int k = 1; k < 7; ++k) if (q >= jb.qstart[k]) i = k;
    int local = q - jb.qstart[i];
    float4 v = jb.src[i][local];
    unsigned lo = (unsigned)f2bf(v.x) | ((unsigned)f2bf(v.y) << 16);
    unsigned hi = (unsigned)f2bf(v.z) | ((unsigned)f2bf(v.w) << 16);
    jb.dst[i][local] = make_uint2(lo, hi);
}

// ---------------- CSR build ----------------
__global__ __launch_bounds__(256) void init_kernel(int* __restrict__ d0, int* __restrict__ f0,
                                                   int* __restrict__ d1, int* __restrict__ f1, int n) {
    int i = blockIdx.x * 256 + threadIdx.x;
    if (i < n) { d0[i] = 0; f0[i] = 0; d1[i] = 0; f1[i] = 0; }
}

__global__ __launch_bounds__(256) void hist_kernel(const int* __restrict__ dst0, int* __restrict__ deg0,
                                                   const int* __restrict__ dst1, int* __restrict__ deg1,
                                                   int e0, int e1) {
    int e = blockIdx.x * 256 + threadIdx.x;
    if (e < e0) atomicAdd(&deg0[dst0[e]], 1);
    if (e < e1) atomicAdd(&deg1[dst1[e]], 1);
}

__global__ __launch_bounds__(1024) void scan_kernel(const int* __restrict__ deg0, int* __restrict__ rp0,
                                                    const int* __restrict__ deg1, int* __restrict__ rp1,
                                                    int n) {
    const int* deg = blockIdx.x ? deg1 : deg0;
    int* rp = blockIdx.x ? rp1 : rp0;
    __shared__ int sums[1024];
    int t = threadIdx.x;
    int chunk = (n + 1023) >> 10;
    int lo = t * chunk;
    int hi = min(n, lo + chunk);
    int s = 0;
    for (int i = lo; i < hi; ++i) s += deg[i];
    sums[t] = s;
    __syncthreads();
    for (int off = 1; off < 1024; off <<= 1) {
        int v = (t >= off) ? sums[t - off] : 0;
        __syncthreads();
        sums[t] += v;
        __syncthreads();
    }
    int run = (t == 0) ? 0 : sums[t - 1];
    for (int i = lo; i < hi; ++i) { rp[i] = run; run += deg[i]; }
}

__global__ __launch_bounds__(256) void fill_kernel(
    const int* __restrict__ src0, const int* __restrict__ dst0, const int* __restrict__ rp0,
    int* __restrict__ f0, int* __restrict__ csr0,
    const int* __restrict__ src1, const int* __restrict__ dst1, const int* __restrict__ rp1,
    int* __restrict__ f1, int* __restrict__ csr1, int e0, int e1) {
    int e = blockIdx.x * 256 + threadIdx.x;
    if (e < e0) { int d = dst0[e]; int p = atomicAdd(&f0[d], 1); csr0[rp0[d] + p] = src0[e]; }
    if (e < e1) { int d = dst1[e]; int p = atomicAdd(&f1[d], 1); csr1[rp1[d] + p] = src1[e]; }
}

// ---------------- mean aggregation: bf16 gather, fp32 accum ----------------
// 16 lanes per node, 16B (8 bf16) per lane per neighbor.
__global__ __launch_bounds__(256) void agg_mean_bf16(const u16* __restrict__ X,
                                                     const int* __restrict__ csr,
                                                     const int* __restrict__ rp,
                                                     const int* __restrict__ deg,
                                                     u16* __restrict__ out, int n) {
    int g = (blockIdx.x * 256 + threadIdx.x) >> 4;
    int lane = threadIdx.x & 15;
    if (g >= n) return;
    int start = rp[g];
    int d = deg[g];
    int end = start + d;
    const uint4* X4 = (const uint4*)X;   // 16 uint4 per 128-elem row
    float acc[8] = {0.f, 0.f, 0.f, 0.f, 0.f, 0.f, 0.f, 0.f};
    int e = start;
    for (; e + 1 < end; e += 2) {
        int s0 = csr[e], s1 = csr[e + 1];
        uint4 v0 = X4[(size_t)s0 * 16 + lane];
        uint4 v1 = X4[(size_t)s1 * 16 + lane];
        acc[0] += bf_lo(v0.x) + bf_lo(v1.x); acc[1] += bf_hi(v0.x) + bf_hi(v1.x);
        acc[2] += bf_lo(v0.y) + bf_lo(v1.y); acc[3] += bf_hi(v0.y) + bf_hi(v1.y);
        acc[4] += bf_lo(v0.z) + bf_lo(v1.z); acc[5] += bf_hi(v0.z) + bf_hi(v1.z);
        acc[6] += bf_lo(v0.w) + bf_lo(v1.w); acc[7] += bf_hi(v0.w) + bf_hi(v1.w);
    }
    if (e < end) {
        int s0 = csr[e];
        uint4 v0 = X4[(size_t)s0 * 16 + lane];
        acc[0] += bf_lo(v0.x); acc[1] += bf_hi(v0.x);
        acc[2] += bf_lo(v0.y); acc[3] += bf_hi(v0.y);
        acc[4] += bf_lo(v0.z); acc[5] += bf_hi(v0.z);
        acc[6] += bf_lo(v0.w); acc[7] += bf_hi(v0.w);
    }
    float scale = 1.0f / (float)max(d, 1);
    uint4 r;
    r.x = (unsigned)f2bf(acc[0] * scale) | ((unsigned)f2bf(acc[1] * scale) << 16);
    r.y = (unsigned)f2bf(acc[2] * scale) | ((unsigned)f2bf(acc[3] * scale) << 16);
    r.z = (unsigned)f2bf(acc[4] * scale) | ((unsigned)f2bf(acc[5] * scale) << 16);
    r.w = (unsigned)f2bf(acc[6] * scale) | ((unsigned)f2bf(acc[7] * scale) << 16);
    ((uint4*)out)[(size_t)g * 16 + lane] = r;
}

// ---------------- MFMA GEMM: C = sum_p A_p @ W_p.T + bias [relu], bf16 in/out ----------------
// BM=64, BN=128, K=128 (whole K staged, no K-tile loop). 256 thr = 4 waves.
// A [M,128] bf16 row-major; W [NC,128] bf16 row-major (NT: both K-contiguous).
// 16x16x32 MFMA; frag A/B = 8 contiguous bf16 at k=(lane>>4)*8; C/D col=lane&15,row=(lane>>4)*4+reg.
// LDS stride 136 shorts (272B) -> fragment reads 2-way bank aliased = free.
template <bool RELU>
__global__ __launch_bounds__(256) void mfma_gemm(
    const u16* __restrict__ A0, const u16* __restrict__ W0,
    const u16* __restrict__ A1, const u16* __restrict__ W1,
    const u16* __restrict__ A2, const u16* __restrict__ W2,
    int npair,
    const float* __restrict__ bias0, const float* __restrict__ bias1,
    u16* __restrict__ C, int M, int NC, int mB) {
    __shared__ u16 As[64 * 136];
    __shared__ u16 Bs[128 * 136];
    const int t = threadIdx.x;
    const int rowBase = (blockIdx.x % mB) * 64;
    const int colBase = (blockIdx.x / mB) * 128;
    const int w = t >> 6, lane = t & 63, r = lane & 15, half = lane >> 4;

    const u16* Ap[3] = {A0, A1, A2};
    const u16* Wp[3] = {W0, W1, W2};

    f32x4 acc[8];
#pragma unroll
    for (int i = 0; i < 8; ++i) acc[i] = (f32x4){0.f, 0.f, 0.f, 0.f};

    for (int p = 0; p < npair; ++p) {
        if (p) __syncthreads();
        const uint4* Ag = (const uint4*)Ap[p];
        const uint4* Wg = (const uint4*)Wp[p];
#pragma unroll
        for (int i = 0; i < 4; ++i) {            // A: 64 rows x 16 chunks
            int id = t + 256 * i, row = id >> 4, cc = id & 15;
            int gr = rowBase + row;
            uint4 v = make_uint4(0u, 0u, 0u, 0u);
            if (gr < M) v = Ag[(size_t)gr * 16 + cc];
            *(uint4*)&As[row * 136 + cc * 8] = v;
        }
#pragma unroll
        for (int i = 0; i < 8; ++i) {            // W: 128 rows x 16 chunks
            int id = t + 256 * i, row = id >> 4, cc = id & 15;
            *(uint4*)&Bs[row * 136 + cc * 8] = Wg[(size_t)(colBase + row) * 16 + cc];
        }
        __syncthreads();
        const u16* aB = &As[(w * 16 + r) * 136 + half * 8];
        const u16* bB = &Bs[r * 136 + half * 8];
#pragma unroll
        for (int kk = 0; kk < 4; ++kk) {
            short8 af = *(const short8*)(aB + kk * 32);
#pragma unroll
            for (int ct = 0; ct < 8; ++ct) {
                short8 bf = *(const short8*)(bB + ct * (16 * 136) + kk * 32);
                acc[ct] = __builtin_amdgcn_mfma_f32_16x16x32_bf16(af, bf, acc[ct], 0, 0, 0);
            }
        }
    }

#pragma unroll
    for (int ct = 0; ct < 8; ++ct) {
        int col = colBase + ct * 16 + r;
        float bv = bias0[col];
        if (bias1) bv += bias1[col];
#pragma unroll
        for (int reg = 0; reg < 4; ++reg) {
            int row = rowBase + w * 16 + half * 4 + reg;
            if (row < M) {
                float v = acc[ct][reg] + bv;
                if (RELU) v = fmaxf(v, 0.f);
                C[(size_t)row * NC + col] = f2bf(v);
            }
        }
    }
}

// ---------------- output: out[N,3] = h4(bf16) @ W2.T(fp32) + b2, one wave/row ----------------
__global__ __launch_bounds__(256) void out_kernel(const u16* __restrict__ h4,
                                                  const float* __restrict__ W2,
                                                  const float* __restrict__ b2,
                                                  float* __restrict__ out, int n) {
    int w = (blockIdx.x * 256 + threadIdx.x) >> 6;
    int lane = threadIdx.x & 63;
    if (w >= n) return;
    uint2 hv = ((const uint2*)h4)[(size_t)w * 64 + lane];   // 4 bf16
    float h0 = bf_lo(hv.x), h1 = bf_hi(hv.x), h2 = bf_lo(hv.y), h3 = bf_hi(hv.y);
    float4 w0 = ((const float4*)W2)[0 * 64 + lane];
    float4 w1 = ((const float4*)W2)[1 * 64 + lane];
    float4 w2 = ((const float4*)W2)[2 * 64 + lane];
    float p0 = h0 * w0.x + h1 * w0.y + h2 * w0.z + h3 * w0.w;
    float p1 = h0 * w1.x + h1 * w1.y + h2 * w1.z + h3 * w1.w;
    float p2 = h0 * w2.x + h1 * w2.y + h2 * w2.z + h3 * w2.w;
#pragma unroll
    for (int off = 32; off > 0; off >>= 1) {
        p0 += __shfl_xor(p0, off);
        p1 += __shfl_xor(p1, off);
        p2 += __shfl_xor(p2, off);
    }
    if (lane == 0) {
        out[(size_t)w * 3 + 0] = p0 + b2[0];
        out[(size_t)w * 3 + 1] = p1 + b2[1];
        out[(size_t)w * 3 + 2] = p2 + b2[2];
    }
}

extern "C" void kernel_launch(void* const* d_in, const int* in_sizes, int n_in,
                              void* d_out, int out_size, void* d_ws, size_t ws_size,
                              hipStream_t stream) {
    const float* x   = (const float*)d_in[0];
    const int*   ei0 = (const int*)d_in[1];
    const int*   ei1 = (const int*)d_in[2];
    const float* Wl1 = (const float*)d_in[3];
    const float* bl1 = (const float*)d_in[4];
    const float* Wr1 = (const float*)d_in[5];
    const float* Wl2 = (const float*)d_in[6];
    const float* bl2 = (const float*)d_in[7];
    const float* Wr2 = (const float*)d_in[8];
    const float* Wsk = (const float*)d_in[9];
    const float* bsk = (const float*)d_in[10];
    const float* W1  = (const float*)d_in[11];
    const float* b1  = (const float*)d_in[12];
    const float* W2  = (const float*)d_in[13];
    const float* b2  = (const float*)d_in[14];
    float* out = (float*)d_out;

    const int N  = in_sizes[0] / DD;   // 50000
    const int E0 = in_sizes[1] / 2;    // 800000
    const int E1 = in_sizes[2] / 2;
    const int H  = in_sizes[12];       // 256

    const int* src0 = ei0;      const int* dst0 = ei0 + E0;
    const int* src1 = ei1;      const int* dst1 = ei1 + E1;

    // workspace carve (256B aligned), ~85 MB
    char* wp = (char*)d_ws;
    auto carve = [&](size_t bytes) { char* p = wp; wp += (bytes + 255) & ~(size_t)255; return p; };
    u16* xh   = (u16*)carve((size_t)N * DD * 2);
    u16* aggh = (u16*)carve((size_t)N * DD * 2);
    u16* h1h  = (u16*)carve((size_t)N * DD * 2);
    u16* h3h  = (u16*)carve((size_t)N * DD * 2);
    u16* h4h  = (u16*)carve((size_t)N * H * 2);
    u16* wl1h = (u16*)carve((size_t)DD * DD * 2);
    u16* wr1h = (u16*)carve((size_t)DD * DD * 2);
    u16* wl2h = (u16*)carve((size_t)DD * DD * 2);
    u16* wr2h = (u16*)carve((size_t)DD * DD * 2);
    u16* wsh  = (u16*)carve((size_t)DD * DD * 2);
    u16* w1h  = (u16*)carve((size_t)H * DD * 2);
    int* deg0 = (int*)carve((size_t)N * 4);
    int* rp0  = (int*)carve((size_t)N * 4);
    int* f0   = (int*)carve((size_t)N * 4);
    int* deg1 = (int*)carve((size_t)N * 4);
    int* rp1  = (int*)carve((size_t)N * 4);
    int* f1   = (int*)carve((size_t)N * 4);
    int* csr0 = (int*)carve((size_t)E0 * 4);
    int* csr1 = (int*)carve((size_t)E1 * 4);

    // fused cast: x + 6 weight matrices
    CastJobs jb;
    const float* srcs[7] = {x, Wl1, Wr1, Wl2, Wr2, Wsk, W1};
    u16* dsts[7]         = {xh, wl1h, wr1h, wl2h, wr2h, wsh, w1h};
    int  cnts[7] = {N * DD, DD * DD, DD * DD, DD * DD, DD * DD, DD * DD, H * DD};
    int q = 0;
    for (int i = 0; i < 7; ++i) {
        jb.src[i] = (const float4*)srcs[i];
        jb.dst[i] = (uint2*)dsts[i];
        jb.qstart[i] = q;
        q += cnts[i] / 4;
    }
    jb.qstart[7] = q;

    const int gN   = (N + 255) / 256;
    const int Emax = (E0 > E1) ? E0 : E1;
    const int gE   = (Emax + 255) / 256;
    const int gAgg = (N * 16 + 255) / 256;
    const int mB   = (N + 63) / 64;    // 782

    cast_kernel<<<(q + 255) / 256, 256, 0, stream>>>(jb);
    init_kernel<<<gN, 256, 0, stream>>>(deg0, f0, deg1, f1, N);
    hist_kernel<<<gE, 256, 0, stream>>>(dst0, deg0, dst1, deg1, E0, E1);
    scan_kernel<<<2, 1024, 0, stream>>>(deg0, rp0, deg1, rp1, N);
    fill_kernel<<<gE, 256, 0, stream>>>(src0, dst0, rp0, f0, csr0,
                                        src1, dst1, rp1, f1, csr1, E0, E1);

    // layer 1
    agg_mean_bf16<<<gAgg, 256, 0, stream>>>(xh, csr0, rp0, deg0, aggh, N);
    mfma_gemm<false><<<mB, 256, 0, stream>>>(
        aggh, wl1h, xh, wr1h, nullptr, nullptr, 2, bl1, nullptr, h1h, N, DD, mB);

    // layer 2 + skip
    agg_mean_bf16<<<gAgg, 256, 0, stream>>>(h1h, csr1, rp1, deg1, aggh, N);
    mfma_gemm<false><<<mB, 256, 0, stream>>>(
        aggh, wl2h, h1h, wr2h, xh, wsh, 3, bl2, bsk, h3h, N, DD, mB);

    // MLP hidden (NC=256 -> 2 column blocks)
    mfma_gemm<true><<<mB * (H / 128), 256, 0, stream>>>(
        h3h, w1h, nullptr, nullptr, nullptr, nullptr, 1, b1, nullptr, h4h, N, H, mB);

    // output layer
    const int gOut = (N * 64 + 255) / 256;
    out_kernel<<<gOut, 256, 0, stream>>>(h4h, W2, b2, out, N);
}